// Round 7
// baseline (801.673 us; speedup 1.0000x reference)
//
#include <hip/hip_runtime.h>
#include <stdint.h>

typedef __attribute__((ext_vector_type(8))) short short8;
typedef __attribute__((ext_vector_type(4))) float floatx4;

#define INV_SQRT2F 0.70710678118654752440f

// fragment-ordered bf16 weights (8.5 MB), filled by k_cvt each call
__device__ ushort g_wbuf[4259840];

__device__ __forceinline__ ushort f2bf(float f) {
    union { float f; uint32_t u; } c; c.f = f;
    uint32_t x = c.u;
    return (ushort)((x + 0x7fffu + ((x >> 16) & 1u)) >> 16);  // RTNE
}
__device__ __forceinline__ float softplus100(float x) {
    float z = 100.f * x;
    return fmaxf(x, 0.f) + __logf(1.f + __expf(-fabsf(z))) * 0.01f;
}
__device__ __forceinline__ int swz(int row, int col) {
    return (((col >> 3) ^ (row & 7)) << 3) | (col & 7);
}
// LDS-only barrier: waits lgkmcnt(0) but NOT vmcnt -> global prefetch loads
// stay in flight across the barrier (the compiler's __syncthreads drains vmcnt).
__device__ __forceinline__ void sync_lds() {
    asm volatile("s_waitcnt lgkmcnt(0)" ::: "memory");
    __builtin_amdgcn_s_barrier();
    asm volatile("" ::: "memory");
}

// ---------------- weight cvt + fragment reorder ----------------
// dest per cluster: short8 i8 = (t*K32 + kc)*64 + lane; elem j:
// n = t*16 + (lane&15), k = kc*32 + (lane>>4)*8 + j. Zeros at edges.
struct Seg { const float* s; int off, nout, kw, k32, ttot, nclust; };
struct CvtAll { Seg seg[16]; };

__global__ void k_cvt(CvtAll c) {
    Seg sg = c.seg[blockIdx.y];
    ushort* d = g_wbuf + sg.off;
    const int pcs8 = sg.ttot * sg.k32 * 64;
    const int tot8 = pcs8 * sg.nclust;
    for (int i8 = blockIdx.x * blockDim.x + threadIdx.x; i8 < tot8;
         i8 += gridDim.x * blockDim.x) {
        int cl = i8 / pcs8;
        int r = i8 - cl * pcs8;
        int t = r / (sg.k32 * 64);
        int r2 = r - t * (sg.k32 * 64);
        int kc = r2 >> 6;
        int lane = r2 & 63;
        int n = t * 16 + (lane & 15);
        int kb = kc * 32 + (lane >> 4) * 8;
        const float* src = sg.s + (size_t)cl * sg.nout * sg.kw;
        short8 v = {0, 0, 0, 0, 0, 0, 0, 0};
        if (n < sg.nout) {
#pragma unroll
            for (int j = 0; j < 8; ++j) {
                int k = kb + j;
                if (k < sg.kw) v[j] = (short)f2bf(src[n * sg.kw + k]);
            }
        }
        *(short8*)(d + (size_t)i8 * 8) = v;
    }
}

// ---------------- embedding: 128 rows, cols 0..63 (zeros beyond 38) ----------------
template<int STRIDE>
__device__ void embed128(short* act, const float* pts, int row0, short* inp_sv) {
    for (int idx = threadIdx.x; idx < 128 * 64; idx += 512) {
        int row = idx >> 6, col = idx & 63;
        float v = 0.f;
        if (col < 39) {
            int comp = (col < 3) ? col : (col - 3) % 3;
            float x = pts[(row0 + row) * 3 + comp];
            if (col < 3) v = x;
            else {
                int b = col - 3; int fi = b / 6; int r = b % 6;
                float a = x * (float)(1 << fi);
                v = (r < 3) ? __sinf(a) : __cosf(a);
            }
        }
        act[row * STRIDE + swz(row, col)] = (short)f2bf(v);
        if (inp_sv && col < 39) inp_sv[row * 40 + col] = (short)f2bf(v * INV_SQRT2F);
    }
}

// ---------------- big layer: 128 rows, 8 waves, i=4 t-tiles x j=8 m-tiles ----------------
// Weights read once per block per layer. w0/w1 arrive preloaded (kc=0,1);
// on the final K-iterations the NEXT layer's kc=0,1 are issued into them.
template<int ACT, int STRIDE, int K32>
__device__ __forceinline__ void big_layer(
    short* act, const ushort* __restrict__ Wf, const float* __restrict__ bias,
    int Nout, float scale, bool toLds, float* gOut, int gCol0, int gRow0,
    short8 (&w0)[4], short8 (&w1)[4],
    const ushort* nextW, int nStrideT, int nTtot)
{
    const int tid = threadIdx.x;
    const int wave = tid >> 6, lane = tid & 63;
    const int q = lane >> 4, li = lane & 15;
    const int Ttot = (Nout + 15) >> 4;

    floatx4 acc[4][8];
#pragma unroll
    for (int i = 0; i < 4; ++i)
#pragma unroll
        for (int m = 0; m < 8; ++m) acc[i][m] = (floatx4){0.f, 0.f, 0.f, 0.f};

    bool tv[4]; const ushort* wb[4]; float bs[4];
#pragma unroll
    for (int i = 0; i < 4; ++i) {
        int t = wave + 8 * i;
        tv[i] = t < Ttot;
        wb[i] = Wf + (size_t)t * (K32 * 512) + lane * 8;
        int n = t * 16 + li;
        bs[i] = (tv[i] && n < Nout) ? bias[n] : 0.f;
    }

    auto loadW = [&](int kc, short8 (&w)[4]) {
#pragma unroll
        for (int i = 0; i < 4; ++i)
            if (tv[i]) w[i] = *(const short8*)(wb[i] + kc * 512);
    };
    auto loadNext = [&](int kc, short8 (&w)[4]) {
        if (!nextW) return;
#pragma unroll
        for (int i = 0; i < 4; ++i) {
            int t = wave + 8 * i;
            if (t < nTtot)
                w[i] = *(const short8*)(nextW + (size_t)t * nStrideT + kc * 512 + lane * 8);
        }
    };
    auto step = [&](int kc, short8 (&w)[4]) {
        const int gq = kc * 4 + q;
#pragma unroll
        for (int h = 0; h < 2; ++h) {
            short8 afr[4];
#pragma unroll
            for (int m2 = 0; m2 < 4; ++m2) {
                int row = (h * 4 + m2) * 16 + li;
                afr[m2] = *(const short8*)&act[row * STRIDE + ((gq ^ (row & 7)) << 3)];
            }
#pragma unroll
            for (int i = 0; i < 4; ++i) {
                if (!tv[i]) continue;
#pragma unroll
                for (int m2 = 0; m2 < 4; ++m2)
                    acc[i][h * 4 + m2] = __builtin_amdgcn_mfma_f32_16x16x32_bf16(
                        afr[m2], w[i], acc[i][h * 4 + m2], 0, 0, 0);
            }
        }
    };

#pragma unroll
    for (int kc = 0; kc < K32; kc += 2) {
        step(kc, w0);
        if (kc + 2 < K32) loadW(kc + 2, w0); else loadNext(0, w0);
        step(kc + 1, w1);
        if (kc + 3 < K32) loadW(kc + 3, w1); else loadNext(1, w1);
    }
    sync_lds();  // act reads done before epilogue overwrites (LDS-only wait)
#pragma unroll
    for (int i = 0; i < 4; ++i) {
        if (!tv[i]) continue;
        int n = (wave + 8 * i) * 16 + li;
        if (n >= Nout) continue;
#pragma unroll
        for (int m = 0; m < 8; ++m) {
            int rbase = m * 16 + q * 4;
#pragma unroll
            for (int r = 0; r < 4; ++r) {
                float v = acc[i][m][r] + bs[i];
                if (ACT == 1) v = softplus100(v);
                else if (ACT == 2) v = fmaxf(v, 0.f);
                else if (ACT == 3) v = tanhf(v);
                v *= scale;
                if (toLds) act[(rbase + r) * STRIDE + swz(rbase + r, n)] = (short)f2bf(v);
                else gOut[(size_t)(gRow0 + rbase + r) * 263 + gCol0 + n] = v;
            }
        }
    }
}

// ---------------- small layer (mult net): 128 rows, 8 waves, i=1 x j=8 ----------------
template<int ACT, int K32>
__device__ __forceinline__ void small_layer(
    short* act, const ushort* __restrict__ Wf, const float* __restrict__ bias,
    int Nout, bool toLds, float* gOut, int gCol0, int gRow0,
    short8& w0, short8& w1, const ushort* nextW, int nStrideT, int nTtot)
{
    const int tid = threadIdx.x;
    const int wave = tid >> 6, lane = tid & 63;
    const int q = lane >> 4, li = lane & 15;
    const int Ttot = (Nout + 15) >> 4;
    const int t = wave;
    const bool tv = t < Ttot;
    const ushort* wb = Wf + (size_t)t * (K32 * 512) + lane * 8;
    const int n = t * 16 + li;
    const float bs = (tv && n < Nout) ? bias[n] : 0.f;

    floatx4 acc[8];
#pragma unroll
    for (int m = 0; m < 8; ++m) acc[m] = (floatx4){0.f, 0.f, 0.f, 0.f};

    auto loadW = [&](int kc, short8& w) {
        if (tv) w = *(const short8*)(wb + kc * 512);
    };
    auto loadNext = [&](int kc, short8& w) {
        if (nextW && t < nTtot)
            w = *(const short8*)(nextW + (size_t)t * nStrideT + kc * 512 + lane * 8);
    };
    auto step = [&](int kc, short8& w) {
        const int gq = kc * 4 + q;
#pragma unroll
        for (int h = 0; h < 2; ++h) {
            short8 afr[4];
#pragma unroll
            for (int m2 = 0; m2 < 4; ++m2) {
                int row = (h * 4 + m2) * 16 + li;
                afr[m2] = *(const short8*)&act[row * 128 + ((gq ^ (row & 7)) << 3)];
            }
            if (tv)
#pragma unroll
                for (int m2 = 0; m2 < 4; ++m2)
                    acc[h * 4 + m2] = __builtin_amdgcn_mfma_f32_16x16x32_bf16(
                        afr[m2], w, acc[h * 4 + m2], 0, 0, 0);
        }
    };
#pragma unroll
    for (int kc = 0; kc < K32; kc += 2) {
        step(kc, w0);
        if (kc + 2 < K32) loadW(kc + 2, w0); else loadNext(0, w0);
        step(kc + 1, w1);
        if (kc + 3 < K32) loadW(kc + 3, w1); else loadNext(1, w1);
    }
    sync_lds();
    if (tv && n < Nout) {
#pragma unroll
        for (int m = 0; m < 8; ++m) {
            int rbase = m * 16 + q * 4;
#pragma unroll
            for (int r = 0; r < 4; ++r) {
                float v = acc[m][r] + bs;
                if (ACT == 2) v = fmaxf(v, 0.f);
                else if (ACT == 3) v = tanhf(v);
                if (toLds) act[(rbase + r) * 128 + swz(rbase + r, n)] = (short)f2bf(v);
                else gOut[(size_t)(gRow0 + rbase + r) * 263 + gCol0 + n] = v;
            }
        }
    }
}

// ---------------- implicit network ----------------
struct IP { int iw[9]; const float* ib[9]; };

__global__ __launch_bounds__(512, 2) void k_impl(const float* __restrict__ pts,
                                                 IP p, float* __restrict__ out) {
    __shared__ __align__(16) short act[128 * 512];
    __shared__ short inp_sv[128 * 40];
    const int row0 = blockIdx.x * 128;
    const int wave = threadIdx.x >> 6, lane = threadIdx.x & 63;

    short8 w0[4], w1[4];
    // prefetch layer-0 weights (K32=2) before the embed's sin/cos VALU burst
#pragma unroll
    for (int i = 0; i < 4; ++i) {
        const ushort* b = g_wbuf + p.iw[0] + ((wave + 8 * i) * (2 * 512)) + lane * 8;
        w0[i] = *(const short8*)b;
        w1[i] = *(const short8*)(b + 512);
    }
    embed128<512>(act, pts, row0, inp_sv);
    sync_lds();
    big_layer<1, 512, 2>(act, g_wbuf + p.iw[0], p.ib[0], 512, 1.f, true, nullptr, 0, 0,
                         w0, w1, g_wbuf + p.iw[1], 8192, 32);
    sync_lds();
    big_layer<1, 512, 16>(act, g_wbuf + p.iw[1], p.ib[1], 512, 1.f, true, nullptr, 0, 0,
                          w0, w1, g_wbuf + p.iw[2], 8192, 32);
    sync_lds();
    big_layer<1, 512, 16>(act, g_wbuf + p.iw[2], p.ib[2], 512, 1.f, true, nullptr, 0, 0,
                          w0, w1, g_wbuf + p.iw[3], 8192, 32);
    sync_lds();
    // layer 3: softplus then pre-scale by 1/sqrt(2) (skip-concat scale)
    big_layer<1, 512, 16>(act, g_wbuf + p.iw[3], p.ib[3], 473, INV_SQRT2F, true, nullptr, 0, 0,
                          w0, w1, g_wbuf + p.iw[4], 8192, 32);
    // append inp * 1/sqrt(2) into cols 473..511 (disjoint from epilogue writes)
    for (int idx = threadIdx.x; idx < 128 * 64; idx += 512) {
        int row = idx >> 6, col = idx & 63;
        if (col < 39) act[row * 512 + swz(row, 473 + col)] = inp_sv[row * 40 + col];
    }
    sync_lds();
    big_layer<1, 512, 16>(act, g_wbuf + p.iw[4], p.ib[4], 512, 1.f, true, nullptr, 0, 0,
                          w0, w1, g_wbuf + p.iw[5], 8192, 32);
    sync_lds();
    big_layer<1, 512, 16>(act, g_wbuf + p.iw[5], p.ib[5], 512, 1.f, true, nullptr, 0, 0,
                          w0, w1, g_wbuf + p.iw[6], 8192, 32);
    sync_lds();
    big_layer<1, 512, 16>(act, g_wbuf + p.iw[6], p.ib[6], 512, 1.f, true, nullptr, 0, 0,
                          w0, w1, g_wbuf + p.iw[7], 8192, 32);
    sync_lds();
    big_layer<1, 512, 16>(act, g_wbuf + p.iw[7], p.ib[7], 512, 1.f, true, nullptr, 0, 0,
                          w0, w1, g_wbuf + p.iw[8], 8192, 17);
    sync_lds();
    big_layer<0, 512, 16>(act, g_wbuf + p.iw[8], p.ib[8], 257, 1.f, false, out, 0, row0,
                          w0, w1, nullptr, 0, 0);
}

// ---------------- displacement + multi networks ----------------
struct DMP { int dw[4]; const float* db[4]; int mw[3]; const float* mb[3]; };

__global__ __launch_bounds__(512, 2) void k_dm(const float* __restrict__ pts,
                                               DMP p, float* __restrict__ out,
                                               int nbD, int rpc) {
    __shared__ __align__(16) short act[128 * 512];
    const int bid = blockIdx.x;
    const int wave = threadIdx.x >> 6, lane = threadIdx.x & 63;
    if (bid < nbD) {
        const int row0 = bid * 128;
        short8 w0[4], w1[4];
#pragma unroll
        for (int i = 0; i < 4; ++i) {
            const ushort* b = g_wbuf + p.dw[0] + ((wave + 8 * i) * (2 * 512)) + lane * 8;
            w0[i] = *(const short8*)b;
            w1[i] = *(const short8*)(b + 512);
        }
        embed128<512>(act, pts, row0, nullptr);
        sync_lds();
        big_layer<2, 512, 2>(act, g_wbuf + p.dw[0], p.db[0], 512, 1.f, true, nullptr, 0, 0,
                             w0, w1, g_wbuf + p.dw[1], 8192, 32);
        sync_lds();
        big_layer<2, 512, 16>(act, g_wbuf + p.dw[1], p.db[1], 512, 1.f, true, nullptr, 0, 0,
                              w0, w1, g_wbuf + p.dw[2], 8192, 32);
        sync_lds();
        big_layer<2, 512, 16>(act, g_wbuf + p.dw[2], p.db[2], 512, 1.f, true, nullptr, 0, 0,
                              w0, w1, g_wbuf + p.dw[3], 8192, 1);
        sync_lds();
        big_layer<3, 512, 16>(act, g_wbuf + p.dw[3], p.db[3], 3, 1.f, false, out, 257, row0,
                              w0, w1, nullptr, 0, 0);
    } else {
        const int row0 = (bid - nbD) * 128;
        const int c = row0 / rpc;
        // per-cluster fragment sizes: L0 8192, L1 16384, L2 2048 shorts
        const ushort* m0 = g_wbuf + p.mw[0] + c * 8192;
        const ushort* m1 = g_wbuf + p.mw[1] + c * 16384;
        const ushort* m2 = g_wbuf + p.mw[2] + c * 2048;
        short8 w0, w1;
        {
            const ushort* b = m0 + (size_t)wave * (2 * 512) + lane * 8;
            w0 = *(const short8*)b;
            w1 = *(const short8*)(b + 512);
        }
        embed128<128>(act, pts, row0, nullptr);
        sync_lds();
        small_layer<2, 2>(act, m0, p.mb[0] + c * 128, 128, true, nullptr, 0, 0,
                          w0, w1, m1, 2048, 8);
        sync_lds();
        small_layer<2, 4>(act, m1, p.mb[1] + c * 128, 128, true, nullptr, 0, 0,
                          w0, w1, m2, 2048, 1);
        sync_lds();
        small_layer<3, 4>(act, m2, p.mb[2] + c * 3, 3, false, out, 260, row0,
                          w0, w1, nullptr, 0, 0);
    }
}

extern "C" void kernel_launch(void* const* d_in, const int* in_sizes, int n_in,
                              void* d_out, int out_size, void* d_ws, size_t ws_size,
                              hipStream_t stream) {
    const float* pts = (const float*)d_in[0];
    float* out = (float*)d_out;
    const int N = in_sizes[0] / 3;       // 32768
    const int nbI = N / 128;             // 256
    const int nbD = N / 128;             // 256
    const int nbM = N / 128;             // 256
    const int rpc = N / 64;              // rows per cluster (512)

    const int iN[9] = {512, 512, 512, 473, 512, 512, 512, 512, 257};
    const int iK[9] = {39, 512, 512, 512, 512, 512, 512, 512, 512};
    const int dN[4] = {512, 512, 512, 3};
    const int dK[4] = {39, 512, 512, 512};
    const int mN[3] = {128, 128, 3};
    const int mK[3] = {39, 128, 128};

    CvtAll cv; IP ip; DMP dm;
    int off = 0, seg = 0;
    auto add_seg = [&](const float* src, int nout, int kw, int nclust) -> int {
        int k32 = ((kw + 31) & ~31) / 32;
        int ttot = (nout + 15) >> 4;
        cv.seg[seg].s = src; cv.seg[seg].off = off;
        cv.seg[seg].nout = nout; cv.seg[seg].kw = kw;
        cv.seg[seg].k32 = k32; cv.seg[seg].ttot = ttot; cv.seg[seg].nclust = nclust;
        int my = off;
        off += ttot * k32 * 512 * nclust;
        ++seg;
        return my;
    };
    for (int l = 0; l < 9; ++l) {
        ip.iw[l] = add_seg((const float*)d_in[1 + 2 * l], iN[l], iK[l], 1);
        ip.ib[l] = (const float*)d_in[2 + 2 * l];
    }
    for (int l = 0; l < 4; ++l) {
        dm.dw[l] = add_seg((const float*)d_in[19 + 2 * l], dN[l], dK[l], 1);
        dm.db[l] = (const float*)d_in[20 + 2 * l];
    }
    for (int l = 0; l < 3; ++l) {
        dm.mw[l] = add_seg((const float*)d_in[27 + 2 * l], mN[l], mK[l], 64);
        dm.mb[l] = (const float*)d_in[28 + 2 * l];
    }

    k_cvt<<<dim3(256, 16), 256, 0, stream>>>(cv);
    k_impl<<<nbI, 512, 0, stream>>>(pts, ip, out);
    k_dm<<<nbD + nbM, 512, 0, stream>>>(pts, dm, out, nbD, rpc);
}